// Round 15
// baseline (75.128 us; speedup 1.0000x reference)
//
#include <hip/hip_runtime.h>
#include <hip/hip_bf16.h>

// SemanticDecoder: mean = b@Wmu+bmu; s = b@Wsig+bsig; var = s*s;
// sample = mean + |s|*eps.  B=65536, K=64, D=300. f32 in/out.
// Outputs concatenated: [sample, mean, var], each B*D.
//
// R15 = R14 with the __syncthreads replaced by a LGKM-ONLY barrier.
// __syncthreads emits s_waitcnt vmcnt(0) lgkmcnt(0) before s_barrier ->
// drains the whole 10-quad eps HBM burst at the barrier. Cross-wave
// correctness here needs only the LDS writes visible (lgkmcnt(0)); eps is
// per-thread register state and should retire progressively inside the
// epilogue via counted vmcnt waits (epr[0] used first = oldest = retires
// first). asm has memory clobber (no ds_read hoist) + sched_barrier(0)
// (rule #18).

#define B_ROWS 65536
#define K_DIM 64
#define D_DIM 300
#define NFRAG 19              // ceil(300/16)
#define ROWS_PER_BLOCK 64
#define THREADS 512           // 8 waves = 4 row-tiles x 2 col-halves
#define QPR 75                // float4-quads per row
#define QPB (ROWS_PER_BLOCK * QPR)  // 4800 quads per block
#define EPQ 10                // eps quads per thread (4800/512 -> 9.375)

typedef __fp16 half2v __attribute__((ext_vector_type(2)));
typedef __fp16 half8v __attribute__((ext_vector_type(8)));
typedef float  f32x4  __attribute__((ext_vector_type(4)));
typedef unsigned int u32x4 __attribute__((ext_vector_type(4)));

__device__ __forceinline__ half2v h2(unsigned int u) {
    return __builtin_bit_cast(half2v, u);
}
__device__ __forceinline__ unsigned int pkd(float a, float b) {
    return __builtin_bit_cast(unsigned int, __builtin_amdgcn_cvt_pkrtz(a, b));
}
__device__ __forceinline__ half8v pack8(float4 x, float4 y) {
    half2v p0 = __builtin_amdgcn_cvt_pkrtz(x.x, x.y);
    half2v p1 = __builtin_amdgcn_cvt_pkrtz(x.z, x.w);
    half2v p2 = __builtin_amdgcn_cvt_pkrtz(y.x, y.y);
    half2v p3 = __builtin_amdgcn_cvt_pkrtz(y.z, y.w);
    half8v r;
    r[0] = p0[0]; r[1] = p0[1]; r[2] = p1[0]; r[3] = p1[1];
    r[4] = p2[0]; r[5] = p2[1]; r[6] = p3[0]; r[7] = p3[1];
    return r;
}

// ---- kernel 0: pack W[64][300] f32 -> f16 MFMA B-fragments (d_ws) --------
// unit t = ((m*NFRAG + f)*2 + s)*64 + lane ; holds 8 f16:
//   W_m[k = s*32 + (lane>>4)*8 + e][col = f*16 + (lane&15)], e = 0..7
// (same k-permutation as the A-frag load below => cancels in the dot)
__global__ void pack_w_kernel(const float* __restrict__ Wmu,
                              const float* __restrict__ Wsig,
                              half8v* __restrict__ wpack)
{
    const int t = blockIdx.x * blockDim.x + threadIdx.x;
    const int total = 2 * NFRAG * 2 * 64;  // 4864
    if (t >= total) return;
    const int lane = t & 63;
    const int fs   = t >> 6;
    const int s    = fs & 1;
    const int mf   = fs >> 1;
    const int m    = mf / NFRAG;
    const int f    = mf - m * NFRAG;
    const int col  = f * 16 + (lane & 15);
    const int k0   = s * 32 + (lane >> 4) * 8;
    const float* W = m ? Wsig : Wmu;
    half8v o;
    #pragma unroll
    for (int e = 0; e < 8; ++e) {
        float v = (col < D_DIM) ? W[(size_t)(k0 + e) * D_DIM + col] : 0.f;
        o[e] = (__fp16)v;
    }
    wpack[t] = o;
}

// ---- main kernel ---------------------------------------------------------
__global__ __launch_bounds__(THREADS, 2) void sem_dec_main(
    const float* __restrict__ b,
    const float* __restrict__ bmu,
    const float* __restrict__ bsig,
    const float* __restrict__ eps,
    const half8v* __restrict__ wpack,
    float* __restrict__ out)
{
    __shared__ unsigned int lds_ms[ROWS_PER_BLOCK * D_DIM]; // 76.8 KB

    const int tid  = threadIdx.x;
    const int lane = tid & 63;
    const int wid  = tid >> 6;            // 0..7
    const int rt   = wid >> 1;            // row-tile 0..3
    const int ch   = wid & 1;             // col-half: frags 0-9 / 10-18
    const int row0 = blockIdx.x * ROWS_PER_BLOCK;

    // ---- A fragments FIRST (16 rows x 64 k): row=lane&15, k=(lane>>4)*8+e --
    const int arow = lane & 15;
    const int kg   = lane >> 4;
    const float* bp = b + (size_t)(row0 + rt * 16 + arow) * K_DIM + kg * 8;
    float4 v0 = *reinterpret_cast<const float4*>(bp);
    float4 v1 = *reinterpret_cast<const float4*>(bp + 4);
    float4 v2 = *reinterpret_cast<const float4*>(bp + 32);
    float4 v3 = *reinterpret_cast<const float4*>(bp + 36);
    half8v a0 = pack8(v0, v1);   // k 0..31
    half8v a1 = pack8(v2, v3);   // k 32..63

    const int ccol = lane & 15;
    const int crow = (lane >> 4) * 4;     // + r (m89-verified C/D map)

    #pragma unroll
    for (int fi = 0; fi < 10; ++fi) {
        const int f = ch * 10 + fi;
        if (f >= NFRAG) break;            // ch=1, fi=9
        const int c = f * 16 + ccol;
        const bool cval = (c < D_DIM);
        // B fragments: coalesced 16B/lane loads from L2-hot wpack
        half8v wm0 = wpack[((0 * NFRAG + f) * 2 + 0) * 64 + lane];
        half8v wm1 = wpack[((0 * NFRAG + f) * 2 + 1) * 64 + lane];
        half8v ws0 = wpack[((1 * NFRAG + f) * 2 + 0) * 64 + lane];
        half8v ws1 = wpack[((1 * NFRAG + f) * 2 + 1) * 64 + lane];
        const float biasm = cval ? bmu[c] : 0.f;
        const float biass = cval ? bsig[c] : 0.f;
        f32x4 accm = {biasm, biasm, biasm, biasm};
        f32x4 accs = {biass, biass, biass, biass};
        accm = __builtin_amdgcn_mfma_f32_16x16x32_f16(a0, wm0, accm, 0, 0, 0);
        accm = __builtin_amdgcn_mfma_f32_16x16x32_f16(a1, wm1, accm, 0, 0, 0);
        accs = __builtin_amdgcn_mfma_f32_16x16x32_f16(a0, ws0, accs, 0, 0, 0);
        accs = __builtin_amdgcn_mfma_f32_16x16x32_f16(a1, ws1, accs, 0, 0, 0);
        if (cval) {
            #pragma unroll
            for (int r = 0; r < 4; ++r)   // 2-way bank alias only (free)
                lds_ms[(rt * 16 + crow + r) * D_DIM + c] = pkd(accm[r], accs[r]);
        }
    }

    // ---- eps prefetch LAST: drains inside the epilogue (counted vmcnt) ----
    const size_t gq0 = (size_t)row0 * QPR;
    const f32x4* eps4 = reinterpret_cast<const f32x4*>(eps);
    f32x4 epr[EPQ];
    #pragma unroll
    for (int i = 0; i < EPQ; ++i) {
        const int q = tid + i * THREADS;
        if (q < QPB) epr[i] = __builtin_nontemporal_load(&eps4[gq0 + q]);
    }

    // ---- LGKM-only barrier: sync LDS writes WITHOUT draining vmcnt --------
    asm volatile("s_waitcnt lgkmcnt(0)" ::: "memory");
    __builtin_amdgcn_s_barrier();
    __builtin_amdgcn_sched_barrier(0);

    // ---- writeout: pure {ds_read_b128, FMA, 3x nt dwordx4 store} ----------
    const size_t BD = (size_t)B_ROWS * D_DIM;
    f32x4* samp4 = reinterpret_cast<f32x4*>(out);
    f32x4* mean4 = reinterpret_cast<f32x4*>(out + BD);
    f32x4* var4  = reinterpret_cast<f32x4*>(out + 2 * BD);
    const u32x4* lds4 = reinterpret_cast<const u32x4*>(lds_ms);
    #pragma unroll
    for (int i = 0; i < EPQ; ++i) {
        const int q = tid + i * THREADS;
        if (q < QPB) {
            const u32x4 ms = lds4[q];
            const f32x4 e = epr[i];
            const half2v p0 = h2(ms.x), p1 = h2(ms.y);
            const half2v p2 = h2(ms.z), p3 = h2(ms.w);
            f32x4 mv, sv, sm, vr;
            mv.x = (float)p0[0]; sv.x = (float)p0[1];
            mv.y = (float)p1[0]; sv.y = (float)p1[1];
            mv.z = (float)p2[0]; sv.z = (float)p2[1];
            mv.w = (float)p3[0]; sv.w = (float)p3[1];
            sm.x = fmaf(fabsf(sv.x), e.x, mv.x);  vr.x = sv.x * sv.x;
            sm.y = fmaf(fabsf(sv.y), e.y, mv.y);  vr.y = sv.y * sv.y;
            sm.z = fmaf(fabsf(sv.z), e.z, mv.z);  vr.z = sv.z * sv.z;
            sm.w = fmaf(fabsf(sv.w), e.w, mv.w);  vr.w = sv.w * sv.w;
            __builtin_nontemporal_store(sm, &samp4[gq0 + q]);
            __builtin_nontemporal_store(mv, &mean4[gq0 + q]);
            __builtin_nontemporal_store(vr, &var4[gq0 + q]);
        }
    }
}

extern "C" void kernel_launch(void* const* d_in, const int* in_sizes, int n_in,
                              void* d_out, int out_size, void* d_ws, size_t ws_size,
                              hipStream_t stream) {
    const float* b    = (const float*)d_in[0];
    // d_in[1] = labels (unused by the reference outputs)
    const float* Wmu  = (const float*)d_in[2];
    const float* bmu  = (const float*)d_in[3];
    const float* Wsig = (const float*)d_in[4];
    const float* bsig = (const float*)d_in[5];
    const float* eps  = (const float*)d_in[6];
    float* out = (float*)d_out;
    half8v* wpack = (half8v*)d_ws;        // 4864 * 16 B = 77824 B

    hipLaunchKernelGGL(pack_w_kernel, dim3(19), dim3(256), 0, stream,
                       Wmu, Wsig, wpack);
    hipLaunchKernelGGL(sem_dec_main, dim3(B_ROWS / ROWS_PER_BLOCK),
                       dim3(THREADS), 0, stream,
                       b, bmu, bsig, eps, wpack, out);
}

// Round 16
// 72.380 us; speedup vs baseline: 1.0380x; 1.0380x over previous
//
#include <hip/hip_runtime.h>
#include <hip/hip_bf16.h>

// SemanticDecoder: mean = b@Wmu+bmu; s = b@Wsig+bsig; var = s*s;
// sample = mean + |s|*eps.  B=65536, K=64, D=300. f32 in/out.
// Outputs concatenated: [sample, mean, var], each B*D.
//
// R16 = R12 (73us best) with the wave decomposition transposed to kill
// B-frag L2 re-reads: wave w owns frag stripes {w, w+8, w+16} and computes
// ALL 4 row-tiles for them. Each wpack frag loaded ONCE per block
// (76 KB vs 320 KB; -250 MB serialized L2 traffic in the compute phase).
// A-frags x4 per wave in 32 VGPRs. Everything else identical to R12:
// eps-first prefetch, __syncthreads, linear-float4 epilogue.

#define B_ROWS 65536
#define K_DIM 64
#define D_DIM 300
#define NFRAG 19              // ceil(300/16)
#define ROWS_PER_BLOCK 64
#define THREADS 512           // 8 waves; wave w -> frags {w, w+8, w+16}
#define QPR 75                // float4-quads per row
#define QPB (ROWS_PER_BLOCK * QPR)  // 4800 quads per block
#define EPQ 10                // eps quads per thread (4800/512 -> 9.375)

typedef __fp16 half2v __attribute__((ext_vector_type(2)));
typedef __fp16 half8v __attribute__((ext_vector_type(8)));
typedef float  f32x4  __attribute__((ext_vector_type(4)));
typedef unsigned int u32x4 __attribute__((ext_vector_type(4)));

__device__ __forceinline__ half2v h2(unsigned int u) {
    return __builtin_bit_cast(half2v, u);
}
__device__ __forceinline__ unsigned int pkd(float a, float b) {
    return __builtin_bit_cast(unsigned int, __builtin_amdgcn_cvt_pkrtz(a, b));
}
__device__ __forceinline__ half8v pack8(float4 x, float4 y) {
    half2v p0 = __builtin_amdgcn_cvt_pkrtz(x.x, x.y);
    half2v p1 = __builtin_amdgcn_cvt_pkrtz(x.z, x.w);
    half2v p2 = __builtin_amdgcn_cvt_pkrtz(y.x, y.y);
    half2v p3 = __builtin_amdgcn_cvt_pkrtz(y.z, y.w);
    half8v r;
    r[0] = p0[0]; r[1] = p0[1]; r[2] = p1[0]; r[3] = p1[1];
    r[4] = p2[0]; r[5] = p2[1]; r[6] = p3[0]; r[7] = p3[1];
    return r;
}

// ---- kernel 0: pack W[64][300] f32 -> f16 MFMA B-fragments (d_ws) --------
// unit t = ((m*NFRAG + f)*2 + s)*64 + lane ; holds 8 f16:
//   W_m[k = s*32 + (lane>>4)*8 + e][col = f*16 + (lane&15)], e = 0..7
// (same k-permutation as the A-frag load below => cancels in the dot)
__global__ void pack_w_kernel(const float* __restrict__ Wmu,
                              const float* __restrict__ Wsig,
                              half8v* __restrict__ wpack)
{
    const int t = blockIdx.x * blockDim.x + threadIdx.x;
    const int total = 2 * NFRAG * 2 * 64;  // 4864
    if (t >= total) return;
    const int lane = t & 63;
    const int fs   = t >> 6;
    const int s    = fs & 1;
    const int mf   = fs >> 1;
    const int m    = mf / NFRAG;
    const int f    = mf - m * NFRAG;
    const int col  = f * 16 + (lane & 15);
    const int k0   = s * 32 + (lane >> 4) * 8;
    const float* W = m ? Wsig : Wmu;
    half8v o;
    #pragma unroll
    for (int e = 0; e < 8; ++e) {
        float v = (col < D_DIM) ? W[(size_t)(k0 + e) * D_DIM + col] : 0.f;
        o[e] = (__fp16)v;
    }
    wpack[t] = o;
}

// ---- main kernel ---------------------------------------------------------
__global__ __launch_bounds__(THREADS, 2) void sem_dec_main(
    const float* __restrict__ b,
    const float* __restrict__ bmu,
    const float* __restrict__ bsig,
    const float* __restrict__ eps,
    const half8v* __restrict__ wpack,
    float* __restrict__ out)
{
    __shared__ unsigned int lds_ms[ROWS_PER_BLOCK * D_DIM]; // 76.8 KB

    const int tid  = threadIdx.x;
    const int lane = tid & 63;
    const int wid  = tid >> 6;            // 0..7: owns frags {wid, wid+8, wid+16}
    const int row0 = blockIdx.x * ROWS_PER_BLOCK;

    // ---- eps prefetch (R12 order: first; best measured) -------------------
    const size_t gq0 = (size_t)row0 * QPR;
    const f32x4* eps4 = reinterpret_cast<const f32x4*>(eps);
    f32x4 epr[EPQ];
    #pragma unroll
    for (int i = 0; i < EPQ; ++i) {
        const int q = tid + i * THREADS;
        if (q < QPB) epr[i] = __builtin_nontemporal_load(&eps4[gq0 + q]);
    }

    // ---- A fragments for ALL 4 row-tiles (32 VGPRs, loaded once) ----------
    // row = rt*16 + (lane&15), k = (lane>>4)*8 + e (+32 for slice 1)
    const int arow = lane & 15;
    const int kg   = lane >> 4;
    half8v a0[4], a1[4];
    #pragma unroll
    for (int rt = 0; rt < 4; ++rt) {
        const float* bp = b + (size_t)(row0 + rt * 16 + arow) * K_DIM + kg * 8;
        float4 v0 = *reinterpret_cast<const float4*>(bp);
        float4 v1 = *reinterpret_cast<const float4*>(bp + 4);
        float4 v2 = *reinterpret_cast<const float4*>(bp + 32);
        float4 v3 = *reinterpret_cast<const float4*>(bp + 36);
        a0[rt] = pack8(v0, v1);   // k 0..31
        a1[rt] = pack8(v2, v3);   // k 32..63
    }

    const int ccol = lane & 15;
    const int crow = (lane >> 4) * 4;     // + r (m89-verified C/D map)

    #pragma unroll
    for (int fi = 0; fi < 3; ++fi) {
        const int f = wid + fi * 8;       // stripes: waves 0-2 get a 3rd frag
        if (f >= NFRAG) break;
        const int c = f * 16 + ccol;
        const bool cval = (c < D_DIM);    // masks f=18 cols 300..303
        // B fragments: loaded ONCE per block (this wave only)
        half8v wm0 = wpack[((0 * NFRAG + f) * 2 + 0) * 64 + lane];
        half8v wm1 = wpack[((0 * NFRAG + f) * 2 + 1) * 64 + lane];
        half8v ws0 = wpack[((1 * NFRAG + f) * 2 + 0) * 64 + lane];
        half8v ws1 = wpack[((1 * NFRAG + f) * 2 + 1) * 64 + lane];
        const float biasm = cval ? bmu[c] : 0.f;
        const float biass = cval ? bsig[c] : 0.f;
        #pragma unroll
        for (int rt = 0; rt < 4; ++rt) {
            f32x4 accm = {biasm, biasm, biasm, biasm};
            f32x4 accs = {biass, biass, biass, biass};
            accm = __builtin_amdgcn_mfma_f32_16x16x32_f16(a0[rt], wm0, accm, 0, 0, 0);
            accm = __builtin_amdgcn_mfma_f32_16x16x32_f16(a1[rt], wm1, accm, 0, 0, 0);
            accs = __builtin_amdgcn_mfma_f32_16x16x32_f16(a0[rt], ws0, accs, 0, 0, 0);
            accs = __builtin_amdgcn_mfma_f32_16x16x32_f16(a1[rt], ws1, accs, 0, 0, 0);
            if (cval) {
                #pragma unroll
                for (int r = 0; r < 4; ++r)   // 2-way bank alias only (free)
                    lds_ms[(rt * 16 + crow + r) * D_DIM + c] =
                        pkd(accm[r], accs[r]);
            }
        }
    }
    __syncthreads();

    // ---- writeout: pure {ds_read_b128, FMA, 3x nt dwordx4 store} ----------
    const size_t BD = (size_t)B_ROWS * D_DIM;
    f32x4* samp4 = reinterpret_cast<f32x4*>(out);
    f32x4* mean4 = reinterpret_cast<f32x4*>(out + BD);
    f32x4* var4  = reinterpret_cast<f32x4*>(out + 2 * BD);
    const u32x4* lds4 = reinterpret_cast<const u32x4*>(lds_ms);
    #pragma unroll
    for (int i = 0; i < EPQ; ++i) {
        const int q = tid + i * THREADS;
        if (q < QPB) {
            const u32x4 ms = lds4[q];
            const f32x4 e = epr[i];
            const half2v p0 = h2(ms.x), p1 = h2(ms.y);
            const half2v p2 = h2(ms.z), p3 = h2(ms.w);
            f32x4 mv, sv, sm, vr;
            mv.x = (float)p0[0]; sv.x = (float)p0[1];
            mv.y = (float)p1[0]; sv.y = (float)p1[1];
            mv.z = (float)p2[0]; sv.z = (float)p2[1];
            mv.w = (float)p3[0]; sv.w = (float)p3[1];
            sm.x = fmaf(fabsf(sv.x), e.x, mv.x);  vr.x = sv.x * sv.x;
            sm.y = fmaf(fabsf(sv.y), e.y, mv.y);  vr.y = sv.y * sv.y;
            sm.z = fmaf(fabsf(sv.z), e.z, mv.z);  vr.z = sv.z * sv.z;
            sm.w = fmaf(fabsf(sv.w), e.w, mv.w);  vr.w = sv.w * sv.w;
            __builtin_nontemporal_store(sm, &samp4[gq0 + q]);
            __builtin_nontemporal_store(mv, &mean4[gq0 + q]);
            __builtin_nontemporal_store(vr, &var4[gq0 + q]);
        }
    }
}

extern "C" void kernel_launch(void* const* d_in, const int* in_sizes, int n_in,
                              void* d_out, int out_size, void* d_ws, size_t ws_size,
                              hipStream_t stream) {
    const float* b    = (const float*)d_in[0];
    // d_in[1] = labels (unused by the reference outputs)
    const float* Wmu  = (const float*)d_in[2];
    const float* bmu  = (const float*)d_in[3];
    const float* Wsig = (const float*)d_in[4];
    const float* bsig = (const float*)d_in[5];
    const float* eps  = (const float*)d_in[6];
    float* out = (float*)d_out;
    half8v* wpack = (half8v*)d_ws;        // 4864 * 16 B = 77824 B

    hipLaunchKernelGGL(pack_w_kernel, dim3(19), dim3(256), 0, stream,
                       Wmu, Wsig, wpack);
    hipLaunchKernelGGL(sem_dec_main, dim3(B_ROWS / ROWS_PER_BLOCK),
                       dim3(THREADS), 0, stream,
                       b, bmu, bsig, eps, wpack, out);
}